// Round 2
// baseline (222.213 us; speedup 1.0000x reference)
//
#include <hip/hip_runtime.h>

#define SEQ 2048
#define HID 2048
#define NH  32
#define NKV 8
#define HD  64

typedef _Float16 f16;
typedef __attribute__((ext_vector_type(4))) _Float16 f16x4;
typedef __attribute__((ext_vector_type(8))) _Float16 f16x8;
typedef __attribute__((ext_vector_type(2))) __fp16   h16x2;
typedef __attribute__((ext_vector_type(4))) float    f32x4;

__device__ __forceinline__ f32x4 mfma_16x16x32(f16x8 a, f16x8 b, f32x4 c) {
    return __builtin_amdgcn_mfma_f32_16x16x32_f16(a, b, c, 0, 0, 0);
}

// async global->LDS, 16B per lane. Global address is PER-LANE (gather);
// LDS dest is wave-uniform base + lane*16 (contiguous).
__device__ __forceinline__ void async16(const void* g, void* l) {
    __builtin_amdgcn_global_load_lds(
        (const __attribute__((address_space(1))) void*)g,
        (__attribute__((address_space(3))) void*)l,
        16, 0, 0);
}

// Bijective XCD remap, column-chunked (m204 variant).
__device__ __forceinline__ void xcd_colmap(int& bx, int& by) {
    int gx = gridDim.x, gy = gridDim.y;
    int nwg = gx * gy;
    int orig = by * gx + bx;
    int q = nwg >> 3, r = nwg & 7;
    int xcd = orig & 7, loc = orig >> 3;
    int wg = (xcd < r ? xcd * (q + 1) : r * (q + 1) + (xcd - r) * q) + loc;
    bx = wg / gy;
    by = wg - bx * gy;
}

// ---------------- prep: 4 weight transposes + x cvt in ONE launch ----------------
__global__ void prep_all(const float* __restrict__ x,
                         const float* __restrict__ wq, const float* __restrict__ wk,
                         const float* __restrict__ wv, const float* __restrict__ wo,
                         f16* __restrict__ xb,
                         f16* __restrict__ Wcat, f16* __restrict__ woT) {
    __shared__ float tile[32][33];
    int z = blockIdx.z;
    int tx = threadIdx.x, ty = threadIdx.y;
    if (z == 4) {   // cvt: 2048*2048 flat
        int idx = (blockIdx.y * 64 + blockIdx.x) * 256 + ty * 32 + tx;
        int i = idx * 4;
        float4 v = *(const float4*)(x + i);
        f16x4 o = { (f16)v.x, (f16)v.y, (f16)v.z, (f16)v.w };
        *(f16x4*)(xb + i) = o;
        return;
    }
    const float* src; f16* dst; int C;
    if      (z == 0) { src = wq; dst = Wcat;                         C = 2048; }
    else if (z == 1) { src = wk; dst = Wcat + (size_t)2048 * 2048;   C = 512;  }
    else if (z == 2) { src = wv; dst = Wcat + (size_t)2560 * 2048;   C = 512;  }
    else             { src = wo; dst = woT;                          C = 2048; }
    int c0 = blockIdx.x * 32, r0 = blockIdx.y * 32;
    if (c0 >= C) return;
#pragma unroll
    for (int i = 0; i < 32; i += 8)
        tile[ty + i][tx] = src[(size_t)(r0 + ty + i) * C + c0 + tx];
    __syncthreads();
#pragma unroll
    for (int i = 0; i < 32; i += 8)
        dst[(size_t)(c0 + ty + i) * 2048 + r0 + tx] = (f16)tile[tx][ty + i];
}

// ---------------- GEMM: C[M,N] = A[M,K] @ BT[N,K]^T ----------------
// 128x128 tile, BK=64, 4 waves 2x2 (each 64x64 out), dbuf staging with
// XOR-swizzled k-chunks. Counted vmcnt(8) double-barrier loop: prefetch
// stays in flight across the barrier (never drain to 0 mid-loop).
// MODE 0: fused QKV epilogue + RoPE; V^T scaled by em[s]=exp2(mask[s]*log2e).
// MODE 1: fp32 row-major direct into Cf.
template <int MODE>
__global__ __launch_bounds__(256)
void gemm_bt(const f16* __restrict__ A, const f16* __restrict__ BT,
             float* __restrict__ Cf, f16* __restrict__ Q, f16* __restrict__ Kk,
             f16* __restrict__ VT, const int* __restrict__ pos,
             const float* __restrict__ mask, int N, int K) {
    __shared__ f16 As[2][128 * 64];   // [row][k-chunk swizzled]
    __shared__ f16 Bs[2][128 * 64];
    int t = threadIdx.x;
    int w = t >> 6, lane = t & 63, quad = lane >> 4, l15 = lane & 15;
    int wm = w >> 1, wn = w & 1;
    int bx = blockIdx.x, by = blockIdx.y;
    xcd_colmap(bx, by);
    int m0 = by * 128, n0 = bx * 128;
    int sw = l15 & 7;

    int r8 = lane >> 3;            // row within 8-row staging group
    int cc = (lane & 7) ^ r8;      // XOR-swizzled global k-chunk
    // wave w stages rows [w*32, w*32+32) of both A and B (4 async16 each)
    const f16* Ag = A  + (size_t)(m0 + w * 32 + r8) * K + cc * 8;
    const f16* Bg = BT + (size_t)(n0 + w * 32 + r8) * K + cc * 8;

    f32x4 acc[4][4] = {};

    // stage tile 0
#pragma unroll
    for (int a = 0; a < 4; a++) {
        async16(Ag + (size_t)(8 * a) * K, &As[0][(w * 32 + 8 * a) * 64]);
        async16(Bg + (size_t)(8 * a) * K, &Bs[0][(w * 32 + 8 * a) * 64]);
    }
    __syncthreads();

    int b = 0;
    for (int kt = 64; kt <= K; kt += 64) {
        if (kt < K) {
#pragma unroll
            for (int a = 0; a < 4; a++) {
                async16(Ag + (size_t)(8 * a) * K + kt, &As[b ^ 1][(w * 32 + 8 * a) * 64]);
                async16(Bg + (size_t)(8 * a) * K + kt, &Bs[b ^ 1][(w * 32 + 8 * a) * 64]);
            }
            // my tile-t loads are the oldest; only the 8 t+1 loads may remain
            asm volatile("s_waitcnt vmcnt(8)" ::: "memory");
        } else {
            asm volatile("s_waitcnt vmcnt(0)" ::: "memory");
        }
        __builtin_amdgcn_s_barrier();          // all waves' tile-t loads landed
        __builtin_amdgcn_sched_barrier(0);     // pin: no ds_read hoists above

        f16x8 af[4][2], bf[4][2];
#pragma unroll
        for (int mi = 0; mi < 4; mi++) {
            int row = wm * 64 + mi * 16 + l15;
#pragma unroll
            for (int kh = 0; kh < 2; kh++)
                af[mi][kh] = *(const f16x8*)(&As[b][row * 64 + ((kh * 4 + quad) ^ sw) * 8]);
        }
#pragma unroll
        for (int ni = 0; ni < 4; ni++) {
            int row = wn * 64 + ni * 16 + l15;
#pragma unroll
            for (int kh = 0; kh < 2; kh++)
                bf[ni][kh] = *(const f16x8*)(&Bs[b][row * 64 + ((kh * 4 + quad) ^ sw) * 8]);
        }
        __builtin_amdgcn_s_setprio(1);
#pragma unroll
        for (int mi = 0; mi < 4; mi++)
#pragma unroll
            for (int ni = 0; ni < 4; ni++) {
                acc[mi][ni] = mfma_16x16x32(af[mi][0], bf[ni][0], acc[mi][ni]);
                acc[mi][ni] = mfma_16x16x32(af[mi][1], bf[ni][1], acc[mi][ni]);
            }
        __builtin_amdgcn_s_setprio(0);
        __builtin_amdgcn_sched_barrier(0);     // pin: nothing sinks below
        __builtin_amdgcn_s_barrier();          // all waves done reading tile t
        b ^= 1;
    }

    int rb  = m0 + wm * 64 + quad * 4;
    int cbh = n0 + wn * 64;          // 64-aligned: one head per wave column
    if (MODE == 0) {
        if (cbh < (NH + NKV) * HD) {
            bool isQ = cbh < NH * HD;
            f16* dst = isQ ? (Q  + (size_t)(cbh >> 6) * SEQ * HD)
                           : (Kk + (size_t)((cbh - NH * HD) >> 6) * SEQ * HD);
            float scale = isQ ? 0.18033688011112042f : 1.0f;  // (1/8)*log2(e)
            float fr[2];
#pragma unroll
            for (int ni = 0; ni < 2; ni++)
                fr[ni] = __builtin_amdgcn_exp2f(
                    (float)(ni * 16 + l15) * -0.41524101186092029f); // -log2(1e4)/32
#pragma unroll
            for (int mi = 0; mi < 4; mi++)
#pragma unroll
                for (int r = 0; r < 4; r++) {
                    int row = rb + mi * 16 + r;
                    float pv = (float)pos[row];
#pragma unroll
                    for (int ni = 0; ni < 2; ni++) {
                        float sn, cs;
                        __sincosf(pv * fr[ni], &sn, &cs);
                        float x1 = acc[mi][ni][r], x2 = acc[mi][ni + 2][r];
                        int d = ni * 16 + l15;
                        dst[(size_t)row * HD + d]      = (f16)(scale * (x1 * cs - x2 * sn));
                        dst[(size_t)row * HD + d + 32] = (f16)(scale * (x2 * cs + x1 * sn));
                    }
                }
        } else {
            // ---- V^T with mask folded in: VT[c2][s] = v * exp2(mask[s]*log2e).
            const float LOG2E = 1.4426950408889634f;
#pragma unroll
            for (int mi = 0; mi < 4; mi++) {
                float4 mv = *(const float4*)(mask + rb + mi * 16);
                float em[4];
#pragma unroll
                for (int r = 0; r < 4; r++)
                    em[r] = __builtin_amdgcn_exp2f((&mv.x)[r] * LOG2E);
#pragma unroll
                for (int ni = 0; ni < 4; ni++) {
                    int c2 = cbh - (NH + NKV) * HD + ni * 16 + l15;
                    f16x4 v4;
                    ((h16x2*)&v4)[0] = __builtin_amdgcn_cvt_pkrtz(
                        acc[mi][ni][0] * em[0], acc[mi][ni][1] * em[1]);
                    ((h16x2*)&v4)[1] = __builtin_amdgcn_cvt_pkrtz(
                        acc[mi][ni][2] * em[2], acc[mi][ni][3] * em[3]);
                    *(f16x4*)(VT + (size_t)c2 * SEQ + rb + mi * 16) = v4;
                }
            }
        }
    } else {
#pragma unroll
        for (int mi = 0; mi < 4; mi++)
#pragma unroll
            for (int ni = 0; ni < 4; ni++)
#pragma unroll
                for (int r = 0; r < 4; r++)
                    Cf[(size_t)(rb + mi * 16 + r) * N + cbh + ni * 16 + l15] =
                        acc[mi][ni][r];
    }
}

// ---------------- fused flash attention: 4 waves x 32 q, 2 blocks/CU ----------
// grid (SEQ/128, NH) = 512 blocks x 256 threads = 2 independent blocks/CU:
// one block computes while the other drains its barrier (round-0's hidden
// win, restored without split-K). Waves 0-1 stage K (permuted rows, per-
// async16 key offsets {0,16,4,20}), waves 2-3 stage V; all 4 share the tile.
// Counted vmcnt(4) + raw s_barrier; mask folded into V; l via em-MFMA.
// Normalizes in-register, writes ctx directly. LDS = 36 KB.
__global__ __launch_bounds__(256)
void attn_fused(const f16* __restrict__ Qb, const f16* __restrict__ Kb,
                const f16* __restrict__ VTb, const float* __restrict__ mask,
                f16* __restrict__ ctx) {
    __shared__ f16 Ks[2][64 * 64];
    __shared__ f16 Vs[2][64 * 64];
    __shared__ f16 Em[SEQ];

    int t = threadIdx.x, w = t >> 6, lane = t & 63, quad = lane >> 4, l15 = lane & 15;
    int h = blockIdx.y, kvh = h >> 2;
    int qbase = blockIdx.x * 128 + w * 32;
    const f16* Qh = Qb  + (size_t)h   * SEQ * HD;
    const f16* Kh = Kb  + (size_t)kvh * SEQ * HD;
    const f16* Vh = VTb + (size_t)kvh * HD * SEQ;
    int sw = l15 & 7;
    const float LOG2E = 1.4426950408889634f;

    // ---- staging: wave role. K waves use permuted rows (g(rr)=k_eff). ----
    int r8 = lane >> 3;
    int cc = (lane & 7) ^ r8;
    bool isK = w < 2;
    int ws2 = isK ? w : (w - 2);
    int lbase = ws2 * 32 * 64;       // this wave's 32 LDS rows
    const f16 *kv0, *kv1, *kv2, *kv3;
    long adv;
    if (isK) {
        // LDS row rr = ws2*32 + 8a + r8 must hold global key
        // g(rr) = 32*(rr>>5) + 8*((rr>>2)&3) + 4*((rr>>4)&1) + (rr&3)
        //       = ws2*32 + {0,16,4,20}[a] + 8*(r8>>2) + (r8&3)
        const f16* bl = Kh + (size_t)(ws2 * 32 + 8 * (r8 >> 2) + (r8 & 3)) * HD + cc * 8;
        kv0 = bl;            kv1 = bl + (size_t)16 * HD;
        kv2 = bl + (size_t)4 * HD;  kv3 = bl + (size_t)20 * HD;
        adv = (long)64 * HD;
    } else {
        const f16* bl = Vh + (size_t)(ws2 * 32 + r8) * SEQ + cc * 8;
        kv0 = bl;                   kv1 = bl + (size_t)8 * SEQ;
        kv2 = bl + (size_t)16 * SEQ; kv3 = bl + (size_t)24 * SEQ;
        adv = 64;
    }

    {   // stage tile 0
        f16* dst = (isK ? &Ks[0][0] : &Vs[0][0]) + lbase;
        async16(kv0, dst);       async16(kv1, dst + 512);
        async16(kv2, dst + 1024); async16(kv3, dst + 1536);
    }

    // ---- stage em = exp2(mask*log2e) for full SEQ (one f16x8 per thread) ----
    {
        int idx = t * 8;
        float4 ma = *(const float4*)(mask + idx);
        float4 mb = *(const float4*)(mask + idx + 4);
        f16x8 e;
        ((h16x2*)&e)[0] = __builtin_amdgcn_cvt_pkrtz(
            __builtin_amdgcn_exp2f(ma.x * LOG2E), __builtin_amdgcn_exp2f(ma.y * LOG2E));
        ((h16x2*)&e)[1] = __builtin_amdgcn_cvt_pkrtz(
            __builtin_amdgcn_exp2f(ma.z * LOG2E), __builtin_amdgcn_exp2f(ma.w * LOG2E));
        ((h16x2*)&e)[2] = __builtin_amdgcn_cvt_pkrtz(
            __builtin_amdgcn_exp2f(mb.x * LOG2E), __builtin_amdgcn_exp2f(mb.y * LOG2E));
        ((h16x2*)&e)[3] = __builtin_amdgcn_cvt_pkrtz(
            __builtin_amdgcn_exp2f(mb.z * LOG2E), __builtin_amdgcn_exp2f(mb.w * LOG2E));
        *(f16x8*)(&Em[idx]) = e;
    }

    // ---- Q fragments (persistent): B-operand of S^T, n = q ----
    f16x8 bq[2][2];
#pragma unroll
    for (int qg = 0; qg < 2; qg++)
#pragma unroll
        for (int ks = 0; ks < 2; ks++)
            bq[qg][ks] = *(const f16x8*)(Qh + (size_t)(qbase + qg * 16 + l15) * HD
                                            + ks * 32 + quad * 8);

    f32x4 o[4][2] = {};          // O^T: [d-tile][q-group]
    f32x4 ol[2]   = {};          // l accumulator (all rows identical)

    int c0 = (quad ^ sw) * 8, c1 = ((4 | quad) ^ sw) * 8;

    // Em ds_writes must be drained before the first barrier makes them visible
    asm volatile("s_waitcnt lgkmcnt(0)" ::: "memory");

    int b = 0;
    const int NT = SEQ / 64;
    for (int ktl = 0; ktl < NT; ktl++) {
        if (ktl + 1 < NT) {
            kv0 += adv; kv1 += adv; kv2 += adv; kv3 += adv;
            f16* dst = (isK ? &Ks[b ^ 1][0] : &Vs[b ^ 1][0]) + lbase;
            async16(kv0, dst);        async16(kv1, dst + 512);
            async16(kv2, dst + 1024); async16(kv3, dst + 1536);
            // my tile-t loads are the oldest; only the 4 t+1 loads may remain
            asm volatile("s_waitcnt vmcnt(4)" ::: "memory");
        } else {
            asm volatile("s_waitcnt vmcnt(0)" ::: "memory");
        }
        __builtin_amdgcn_s_barrier();            // all waves' tile-t loads landed
        __builtin_amdgcn_sched_barrier(0);       // pin: no ds_read hoists above

        const f16* Kb_ = &Ks[b][0];
        const f16* Vb_ = &Vs[b][0];

        // ---- S^T = K @ Q^T (keys in permuted order) ----
        f32x4 st[4][2] = {};
        __builtin_amdgcn_s_setprio(1);
#pragma unroll
        for (int ni = 0; ni < 4; ni++) {
            const f16* kr = Kb_ + (ni * 16 + l15) * 64;
            f16x8 ak0 = *(const f16x8*)(kr + c0);
            f16x8 ak1 = *(const f16x8*)(kr + c1);
#pragma unroll
            for (int qg = 0; qg < 2; qg++) {
                st[ni][qg] = mfma_16x16x32(ak0, bq[qg][0], st[ni][qg]);
                st[ni][qg] = mfma_16x16x32(ak1, bq[qg][1], st[ni][qg]);
            }
        }
        __builtin_amdgcn_s_setprio(0);
        // ---- p = exp2(s) (mask lives in V); pack via cvt_pkrtz ----
        f16x8 pb[2][2];   // [qg][ks]
#pragma unroll
        for (int ni = 0; ni < 4; ni++)
#pragma unroll
            for (int qg = 0; qg < 2; qg++) {
                h16x2 lo = __builtin_amdgcn_cvt_pkrtz(
                    __builtin_amdgcn_exp2f(st[ni][qg][0]),
                    __builtin_amdgcn_exp2f(st[ni][qg][1]));
                h16x2 hi = __builtin_amdgcn_cvt_pkrtz(
                    __builtin_amdgcn_exp2f(st[ni][qg][2]),
                    __builtin_amdgcn_exp2f(st[ni][qg][3]));
                ((h16x2*)&pb[qg][ni >> 1])[(ni & 1) * 2]     = lo;
                ((h16x2*)&pb[qg][ni >> 1])[(ni & 1) * 2 + 1] = hi;
            }
        // ---- l += em-row @ P (MFMA; every output row = l[q]) ----
        f16x8 em0 = *(const f16x8*)(&Em[ktl * 64 + quad * 8]);
        f16x8 em1 = *(const f16x8*)(&Em[ktl * 64 + 32 + quad * 8]);
        __builtin_amdgcn_s_setprio(1);
#pragma unroll
        for (int qg = 0; qg < 2; qg++) {
            ol[qg] = mfma_16x16x32(em0, pb[qg][0], ol[qg]);
            ol[qg] = mfma_16x16x32(em1, pb[qg][1], ol[qg]);
        }
        // ---- O^T += V^T @ P ----
#pragma unroll
        for (int dt = 0; dt < 4; dt++) {
            const f16* vr = Vb_ + (dt * 16 + l15) * 64;
            f16x8 av0 = *(const f16x8*)(vr + c0);
            f16x8 av1 = *(const f16x8*)(vr + c1);
#pragma unroll
            for (int qg = 0; qg < 2; qg++) {
                o[dt][qg] = mfma_16x16x32(av0, pb[qg][0], o[dt][qg]);
                o[dt][qg] = mfma_16x16x32(av1, pb[qg][1], o[dt][qg]);
            }
        }
        __builtin_amdgcn_s_setprio(0);
        __builtin_amdgcn_sched_barrier(0);       // pin: nothing sinks below
        __builtin_amdgcn_s_barrier();            // all waves done reading tile t
        b ^= 1;
    }

    // ---- normalize in-register, write ctx[row][h*64+d] directly ----
    float inv[2] = { 1.0f / ol[0][0], 1.0f / ol[1][0] };
#pragma unroll
    for (int dt = 0; dt < 4; dt++)
#pragma unroll
        for (int qg = 0; qg < 2; qg++) {
            f16x4 v4;
            ((h16x2*)&v4)[0] = __builtin_amdgcn_cvt_pkrtz(
                o[dt][qg][0] * inv[qg], o[dt][qg][1] * inv[qg]);
            ((h16x2*)&v4)[1] = __builtin_amdgcn_cvt_pkrtz(
                o[dt][qg][2] * inv[qg], o[dt][qg][3] * inv[qg]);
            *(f16x4*)(ctx + (size_t)(qbase + qg * 16 + l15) * (NH * HD)
                          + h * HD + dt * 16 + quad * 4) = v4;
        }
}

// ---------------- launch ----------------
extern "C" void kernel_launch(void* const* d_in, const int* in_sizes, int n_in,
                              void* d_out, int out_size, void* d_ws, size_t ws_size,
                              hipStream_t stream) {
    const float* x    = (const float*)d_in[0];
    const float* mask = (const float*)d_in[1];
    const int*   pos  = (const int*)  d_in[2];
    const float* wq   = (const float*)d_in[3];
    const float* wk   = (const float*)d_in[4];
    const float* wv   = (const float*)d_in[5];
    const float* wo   = (const float*)d_in[6];
    float* out = (float*)d_out;

    char* ws = (char*)d_ws;
    // phase 1-2: xb [0,8M), Wcat [8,20M), woT [20,28M), Qb [28,36M),
    //            Kb [36,38M), VTb [38,40M)
    // phase 3:   ctx [0,8M) (xb dead after gemm0)
    // phase 4:   gemm1 reads ctx + woT
    f16*   xb    = (f16*)(ws);
    f16*   Wcat  = (f16*)(ws + ((size_t)8  << 20));
    f16*   woT   = (f16*)(ws + ((size_t)20 << 20));
    f16*   Qb    = (f16*)(ws + ((size_t)28 << 20));
    f16*   Kb    = (f16*)(ws + ((size_t)36 << 20));
    f16*   VTb   = (f16*)(ws + ((size_t)38 << 20));
    f16*   ctx   = (f16*)(ws);

    prep_all<<<dim3(64, 64, 5), dim3(32, 8), 0, stream>>>(
        x, wq, wk, wv, wo, xb, Wcat, woT);

    // fused Q/K/V projection + RoPE + mask-folded V: C[2048,3072] = xb @ Wcat^T
    gemm_bt<0><<<dim3(3072 / 128, 2048 / 128), 256, 0, stream>>>(
        xb, Wcat, nullptr, Qb, Kb, VTb, pos, mask, 3072, 2048);

    attn_fused<<<dim3(SEQ / 128, NH), 256, 0, stream>>>(
        Qb, Kb, VTb, mask, ctx);

    // out = ctx @ wo (fp32 direct)
    gemm_bt<1><<<dim3(2048 / 128, 2048 / 128), 256, 0, stream>>>(
        ctx, woT, out, nullptr, nullptr, nullptr, nullptr, nullptr, 2048, 2048);
}

// Round 3
// 204.429 us; speedup vs baseline: 1.0870x; 1.0870x over previous
//
#include <hip/hip_runtime.h>

#define SEQ 2048
#define HID 2048
#define NH  32
#define NKV 8
#define HD  64

typedef _Float16 f16;
typedef __attribute__((ext_vector_type(4))) _Float16 f16x4;
typedef __attribute__((ext_vector_type(8))) _Float16 f16x8;
typedef __attribute__((ext_vector_type(2))) __fp16   h16x2;
typedef __attribute__((ext_vector_type(4))) float    f32x4;

__device__ __forceinline__ f32x4 mfma_16x16x32(f16x8 a, f16x8 b, f32x4 c) {
    return __builtin_amdgcn_mfma_f32_16x16x32_f16(a, b, c, 0, 0, 0);
}

// async global->LDS, 16B per lane. Global address is PER-LANE (gather);
// LDS dest is wave-uniform base + lane*16 (contiguous).
__device__ __forceinline__ void async16(const void* g, void* l) {
    __builtin_amdgcn_global_load_lds(
        (const __attribute__((address_space(1))) void*)g,
        (__attribute__((address_space(3))) void*)l,
        16, 0, 0);
}

// Bijective XCD remap, column-chunked (m204 variant).
__device__ __forceinline__ void xcd_colmap(int& bx, int& by) {
    int gx = gridDim.x, gy = gridDim.y;
    int nwg = gx * gy;
    int orig = by * gx + bx;
    int q = nwg >> 3, r = nwg & 7;
    int xcd = orig & 7, loc = orig >> 3;
    int wg = (xcd < r ? xcd * (q + 1) : r * (q + 1) + (xcd - r) * q) + loc;
    bx = wg / gy;
    by = wg - bx * gy;
}

// ---------------- prep: 4 weight transposes + x cvt in ONE launch ----------------
__global__ void prep_all(const float* __restrict__ x,
                         const float* __restrict__ wq, const float* __restrict__ wk,
                         const float* __restrict__ wv, const float* __restrict__ wo,
                         f16* __restrict__ xb,
                         f16* __restrict__ Wcat, f16* __restrict__ woT) {
    __shared__ float tile[32][33];
    int z = blockIdx.z;
    int tx = threadIdx.x, ty = threadIdx.y;
    if (z == 4) {   // cvt: 2048*2048 flat
        int idx = (blockIdx.y * 64 + blockIdx.x) * 256 + ty * 32 + tx;
        int i = idx * 4;
        float4 v = *(const float4*)(x + i);
        f16x4 o = { (f16)v.x, (f16)v.y, (f16)v.z, (f16)v.w };
        *(f16x4*)(xb + i) = o;
        return;
    }
    const float* src; f16* dst; int C;
    if      (z == 0) { src = wq; dst = Wcat;                         C = 2048; }
    else if (z == 1) { src = wk; dst = Wcat + (size_t)2048 * 2048;   C = 512;  }
    else if (z == 2) { src = wv; dst = Wcat + (size_t)2560 * 2048;   C = 512;  }
    else             { src = wo; dst = woT;                          C = 2048; }
    int c0 = blockIdx.x * 32, r0 = blockIdx.y * 32;
    if (c0 >= C) return;
#pragma unroll
    for (int i = 0; i < 32; i += 8)
        tile[ty + i][tx] = src[(size_t)(r0 + ty + i) * C + c0 + tx];
    __syncthreads();
#pragma unroll
    for (int i = 0; i < 32; i += 8)
        dst[(size_t)(c0 + ty + i) * 2048 + r0 + tx] = (f16)tile[tx][ty + i];
}

// ---------------- GEMM: C[M,N] = A[M,K] @ BT[N,K]^T (round-1 known-good) -------
// 64(M) x 128(N) tile, BK=64, 4 waves 2x2, dbuf staging with XOR-swizzled
// k-chunks (conflict-free b128 reads). Plain __syncthreads loop (pins and
// setprio regressed here — m190/m137 lockstep-GEMM null).
// MODE 0: fused QKV epilogue + RoPE; V^T scaled by em[s]=exp2(mask[s]*log2e).
// MODE 1: fp32 row-major direct into Cf.
template <int MODE>
__global__ __launch_bounds__(256)
void gemm_bt(const f16* __restrict__ A, const f16* __restrict__ BT,
             float* __restrict__ Cf, f16* __restrict__ Q, f16* __restrict__ Kk,
             f16* __restrict__ VT, const int* __restrict__ pos,
             const float* __restrict__ mask, int N, int K) {
    __shared__ f16 As[2][64 * 64];    // [row][k-chunk swizzled]
    __shared__ f16 Bs[2][128 * 64];
    int t = threadIdx.x;
    int w = t >> 6, lane = t & 63, quad = lane >> 4, l15 = lane & 15;
    int wm = w >> 1, wn = w & 1;
    int bx = blockIdx.x, by = blockIdx.y;
    xcd_colmap(bx, by);
    int m0 = by * 64, n0 = bx * 128;
    int sw = l15 & 7;

    int r8 = lane >> 3;            // row within 8-row staging group
    int cc = (lane & 7) ^ r8;      // XOR-swizzled global k-chunk
    const f16* Ag0 = A  + (size_t)(m0 + w * 16 + r8) * K + cc * 8;
    const f16* Ag1 = Ag0 + (size_t)8 * K;
    const f16* Bg  = BT + (size_t)(n0 + w * 32 + r8) * K + cc * 8;

    f32x4 acc[2][4] = {};

    // stage tile 0
    async16(Ag0, &As[0][w * 1024]);
    async16(Ag1, &As[0][w * 1024 + 512]);
#pragma unroll
    for (int g = 0; g < 4; g++)
        async16(Bg + (size_t)(8 * g) * K, &Bs[0][w * 2048 + g * 512]);
    __syncthreads();

    int b = 0;
    for (int kt = 64; kt <= K; kt += 64) {
        if (kt < K) {
            async16(Ag0 + kt, &As[b ^ 1][w * 1024]);
            async16(Ag1 + kt, &As[b ^ 1][w * 1024 + 512]);
#pragma unroll
            for (int g = 0; g < 4; g++)
                async16(Bg + (size_t)(8 * g) * K + kt, &Bs[b ^ 1][w * 2048 + g * 512]);
        }
        f16x8 af[2][2], bf[4][2];
#pragma unroll
        for (int mi = 0; mi < 2; mi++) {
            int row = wm * 32 + mi * 16 + l15;
#pragma unroll
            for (int kh = 0; kh < 2; kh++)
                af[mi][kh] = *(const f16x8*)(&As[b][row * 64 + ((kh * 4 + quad) ^ sw) * 8]);
        }
#pragma unroll
        for (int ni = 0; ni < 4; ni++) {
            int row = wn * 64 + ni * 16 + l15;
#pragma unroll
            for (int kh = 0; kh < 2; kh++)
                bf[ni][kh] = *(const f16x8*)(&Bs[b][row * 64 + ((kh * 4 + quad) ^ sw) * 8]);
        }
#pragma unroll
        for (int mi = 0; mi < 2; mi++)
#pragma unroll
            for (int ni = 0; ni < 4; ni++) {
                acc[mi][ni] = mfma_16x16x32(af[mi][0], bf[ni][0], acc[mi][ni]);
                acc[mi][ni] = mfma_16x16x32(af[mi][1], bf[ni][1], acc[mi][ni]);
            }
        __syncthreads();
        b ^= 1;
    }

    int rb  = m0 + wm * 32 + quad * 4;
    int cbh = n0 + wn * 64;          // 64-aligned: one head per wave column
    if (MODE == 0) {
        if (cbh < (NH + NKV) * HD) {
            bool isQ = cbh < NH * HD;
            f16* dst = isQ ? (Q  + (size_t)(cbh >> 6) * SEQ * HD)
                           : (Kk + (size_t)((cbh - NH * HD) >> 6) * SEQ * HD);
            float scale = isQ ? 0.18033688011112042f : 1.0f;  // (1/8)*log2(e)
            float fr[2];
#pragma unroll
            for (int ni = 0; ni < 2; ni++)
                fr[ni] = __builtin_amdgcn_exp2f(
                    (float)(ni * 16 + l15) * -0.41524101186092029f); // -log2(1e4)/32
#pragma unroll
            for (int mi = 0; mi < 2; mi++)
#pragma unroll
                for (int r = 0; r < 4; r++) {
                    int row = rb + mi * 16 + r;
                    float pv = (float)pos[row];
#pragma unroll
                    for (int ni = 0; ni < 2; ni++) {
                        float sn, cs;
                        __sincosf(pv * fr[ni], &sn, &cs);
                        float x1 = acc[mi][ni][r], x2 = acc[mi][ni + 2][r];
                        int d = ni * 16 + l15;
                        dst[(size_t)row * HD + d]      = (f16)(scale * (x1 * cs - x2 * sn));
                        dst[(size_t)row * HD + d + 32] = (f16)(scale * (x2 * cs + x1 * sn));
                    }
                }
        } else {
            // ---- V^T with mask folded in: VT[c2][s] = v * exp2(mask[s]*log2e).
            const float LOG2E = 1.4426950408889634f;
#pragma unroll
            for (int mi = 0; mi < 2; mi++) {
                float4 mv = *(const float4*)(mask + rb + mi * 16);
                float em[4];
#pragma unroll
                for (int r = 0; r < 4; r++)
                    em[r] = __builtin_amdgcn_exp2f((&mv.x)[r] * LOG2E);
#pragma unroll
                for (int ni = 0; ni < 4; ni++) {
                    int c2 = cbh - (NH + NKV) * HD + ni * 16 + l15;
                    f16x4 v4;
                    ((h16x2*)&v4)[0] = __builtin_amdgcn_cvt_pkrtz(
                        acc[mi][ni][0] * em[0], acc[mi][ni][1] * em[1]);
                    ((h16x2*)&v4)[1] = __builtin_amdgcn_cvt_pkrtz(
                        acc[mi][ni][2] * em[2], acc[mi][ni][3] * em[3]);
                    *(f16x4*)(VT + (size_t)c2 * SEQ + rb + mi * 16) = v4;
                }
            }
        }
    } else {
#pragma unroll
        for (int mi = 0; mi < 2; mi++)
#pragma unroll
            for (int ni = 0; ni < 4; ni++)
#pragma unroll
                for (int r = 0; r < 4; r++)
                    Cf[(size_t)(rb + mi * 16 + r) * N + cbh + ni * 16 + l15] =
                        acc[mi][ni][r];
    }
}

// ---------------- fused flash attention: 8 waves, KVBLK=128 (16 tiles) ---------
// grid (SEQ/256, NH) = 256 blocks x 512 threads. Halved barrier count vs
// round-1 (16 tiles of 128 keys instead of 32 of 64): the per-tile fixed
// sync/drain overhead (~2000 cy) amortizes over 2x compute. Each 128-key
// tile is two independent 64-key halves; LDS K row rho holds key
// 64*(rho>>6) + g(rho&63) (the PV-alignment permutation, verified inverse).
// Waves 0-3 stage K halves, waves 4-7 stage V^T (128-wide rows, XOR-swizzled
// 16B chunks). Counted vmcnt(4) + raw s_barrier (never drain mid-loop).
// Mask folded into V; l via em-MFMA; normalize in-register, write ctx.
// LDS = 68 KB.
__global__ __launch_bounds__(512)
void attn_fused(const f16* __restrict__ Qb, const f16* __restrict__ Kb,
                const f16* __restrict__ VTb, const float* __restrict__ mask,
                f16* __restrict__ ctx) {
    __shared__ f16 Ks[2][128 * 64];
    __shared__ f16 Vs[2][64 * 128];
    __shared__ f16 Em[SEQ];

    int t = threadIdx.x, w = t >> 6, lane = t & 63, quad = lane >> 4, l15 = lane & 15;
    int h = blockIdx.y, kvh = h >> 2;
    int qbase = blockIdx.x * 256 + w * 32;
    const f16* Qh = Qb  + (size_t)h   * SEQ * HD;
    const f16* Kh = Kb  + (size_t)kvh * SEQ * HD;
    const f16* Vh = VTb + (size_t)kvh * HD * SEQ;
    int sw = l15 & 7;
    const float LOG2E = 1.4426950408889634f;

    // ---- staging: wave role ----
    int r8 = lane >> 3;
    int cc = (lane & 7) ^ r8;      // XOR-swizzled chunk within 64-f16 K row
    bool isK = w < 4;
    const f16 *kv0, *kv1, *kv2, *kv3;
    long adv;
    int lbase;
    if (isK) {
        // LDS K row rr = w*32 + 8a + r8 holds key 64*(w>>1) + g((w&1)*32+8a+r8)
        // with per-a offsets {0,16,4,20} (same derivation as round 1).
        int khalf = w >> 1, ws2 = w & 1;
        const f16* bl = Kh + (size_t)(khalf * 64 + ws2 * 32
                                      + 8 * (r8 >> 2) + (r8 & 3)) * HD + cc * 8;
        kv0 = bl;                   kv1 = bl + (size_t)16 * HD;
        kv2 = bl + (size_t)4 * HD;  kv3 = bl + (size_t)20 * HD;
        adv = (long)128 * HD;
        lbase = w * 32 * 64;        // rows w*32.. (64 f16/row)
    } else {
        // V^T rows are 128 f16 (256B). async16 = 4 rows; lane: r4=lane>>4,
        // pos16=lane&15 holds global chunk pos16^(row&7).
        int wv = w - 4;
        int r4 = lane >> 4, p16 = lane & 15;
        const f16* ve = Vh + (size_t)(wv * 16 + r4) * SEQ + (p16 ^ r4) * 8;
        const f16* vo = Vh + (size_t)(wv * 16 + 4 + r4) * SEQ + (p16 ^ (4 + r4)) * 8;
        kv0 = ve;                   kv1 = vo;
        kv2 = ve + (size_t)8 * SEQ; kv3 = vo + (size_t)8 * SEQ;
        adv = 128;
        lbase = wv * 16 * 128;      // rows wv*16.. (128 f16/row)
    }

    {   // stage tile 0 (4 async16/wave)
        f16* dst = (isK ? &Ks[0][0] : &Vs[0][0]) + lbase;
        async16(kv0, dst);        async16(kv1, dst + 512);
        async16(kv2, dst + 1024); async16(kv3, dst + 1536);
    }

    // ---- stage em = exp2(mask*log2e) for full SEQ (one f16x4 per thread) ----
    {
        int idx = t * 4;
        float4 mv = *(const float4*)(mask + idx);
        f16x4 e;
        ((h16x2*)&e)[0] = __builtin_amdgcn_cvt_pkrtz(
            __builtin_amdgcn_exp2f(mv.x * LOG2E), __builtin_amdgcn_exp2f(mv.y * LOG2E));
        ((h16x2*)&e)[1] = __builtin_amdgcn_cvt_pkrtz(
            __builtin_amdgcn_exp2f(mv.z * LOG2E), __builtin_amdgcn_exp2f(mv.w * LOG2E));
        *(f16x4*)(&Em[idx]) = e;
    }

    // ---- Q fragments (persistent): B-operand of S^T, n = q ----
    f16x8 bq[2][2];
#pragma unroll
    for (int qg = 0; qg < 2; qg++)
#pragma unroll
        for (int ks = 0; ks < 2; ks++)
            bq[qg][ks] = *(const f16x8*)(Qh + (size_t)(qbase + qg * 16 + l15) * HD
                                            + ks * 32 + quad * 8);

    f32x4 o[4][2] = {};          // O^T: [d-tile][q-group]
    f32x4 ol[2]   = {};          // l accumulator (all rows identical)

    int c0 = (quad ^ sw) * 8, c1 = ((4 | quad) ^ sw) * 8;

    // Em ds_writes must be drained before the first barrier publishes them
    asm volatile("s_waitcnt lgkmcnt(0)" ::: "memory");

    int b = 0;
    const int NT = SEQ / 128;    // 16 tiles
    for (int ktl = 0; ktl < NT; ktl++) {
        if (ktl + 1 < NT) {
            kv0 += adv; kv1 += adv; kv2 += adv; kv3 += adv;
            f16* dst = (isK ? &Ks[b ^ 1][0] : &Vs[b ^ 1][0]) + lbase;
            async16(kv0, dst);        async16(kv1, dst + 512);
            async16(kv2, dst + 1024); async16(kv3, dst + 1536);
            // my tile-t loads are the oldest; only the 4 t+1 loads may remain
            asm volatile("s_waitcnt vmcnt(4)" ::: "memory");
        } else {
            asm volatile("s_waitcnt vmcnt(0)" ::: "memory");
        }
        __builtin_amdgcn_s_barrier();            // all waves' tile-t loads landed
        __builtin_amdgcn_sched_barrier(0);       // pin: no ds_read hoists above

        const f16* Kb_ = &Ks[b][0];
        const f16* Vb_ = &Vs[b][0];

#pragma unroll
        for (int half = 0; half < 2; half++) {
            // ---- S^T = K @ Q^T (keys in permuted order within half) ----
            f32x4 st[4][2] = {};
            __builtin_amdgcn_s_setprio(1);
#pragma unroll
            for (int ni = 0; ni < 4; ni++) {
                const f16* kr = Kb_ + (half * 64 + ni * 16 + l15) * 64;
                f16x8 ak0 = *(const f16x8*)(kr + c0);
                f16x8 ak1 = *(const f16x8*)(kr + c1);
#pragma unroll
                for (int qg = 0; qg < 2; qg++) {
                    st[ni][qg] = mfma_16x16x32(ak0, bq[qg][0], st[ni][qg]);
                    st[ni][qg] = mfma_16x16x32(ak1, bq[qg][1], st[ni][qg]);
                }
            }
            __builtin_amdgcn_s_setprio(0);
            // ---- p = exp2(s) (mask lives in V); pack via cvt_pkrtz ----
            f16x8 pb[2][2];   // [qg][k-slice within half]
#pragma unroll
            for (int ni = 0; ni < 4; ni++)
#pragma unroll
                for (int qg = 0; qg < 2; qg++) {
                    h16x2 lo = __builtin_amdgcn_cvt_pkrtz(
                        __builtin_amdgcn_exp2f(st[ni][qg][0]),
                        __builtin_amdgcn_exp2f(st[ni][qg][1]));
                    h16x2 hi = __builtin_amdgcn_cvt_pkrtz(
                        __builtin_amdgcn_exp2f(st[ni][qg][2]),
                        __builtin_amdgcn_exp2f(st[ni][qg][3]));
                    ((h16x2*)&pb[qg][ni >> 1])[(ni & 1) * 2]     = lo;
                    ((h16x2*)&pb[qg][ni >> 1])[(ni & 1) * 2 + 1] = hi;
                }
            // ---- l += em-row @ P (MFMA; every output row = l[q]) ----
            f16x8 em0 = *(const f16x8*)(&Em[ktl * 128 + half * 64 + quad * 8]);
            f16x8 em1 = *(const f16x8*)(&Em[ktl * 128 + half * 64 + 32 + quad * 8]);
            __builtin_amdgcn_s_setprio(1);
#pragma unroll
            for (int qg = 0; qg < 2; qg++) {
                ol[qg] = mfma_16x16x32(em0, pb[qg][0], ol[qg]);
                ol[qg] = mfma_16x16x32(em1, pb[qg][1], ol[qg]);
            }
            // ---- O^T += V^T @ P ----
#pragma unroll
            for (int dt = 0; dt < 4; dt++) {
                const f16* vr = Vb_ + (dt * 16 + l15) * 128 + half * 64;
                f16x8 av0 = *(const f16x8*)(vr + c0);
                f16x8 av1 = *(const f16x8*)(vr + c1);
#pragma unroll
                for (int qg = 0; qg < 2; qg++) {
                    o[dt][qg] = mfma_16x16x32(av0, pb[qg][0], o[dt][qg]);
                    o[dt][qg] = mfma_16x16x32(av1, pb[qg][1], o[dt][qg]);
                }
            }
            __builtin_amdgcn_s_setprio(0);
        }
        __builtin_amdgcn_sched_barrier(0);       // pin: nothing sinks below
        __builtin_amdgcn_s_barrier();            // all waves done reading tile t
        b ^= 1;
    }

    // ---- normalize in-register, write ctx[row][h*64+d] directly ----
    float inv[2] = { 1.0f / ol[0][0], 1.0f / ol[1][0] };
#pragma unroll
    for (int dt = 0; dt < 4; dt++)
#pragma unroll
        for (int qg = 0; qg < 2; qg++) {
            f16x4 v4;
            ((h16x2*)&v4)[0] = __builtin_amdgcn_cvt_pkrtz(
                o[dt][qg][0] * inv[qg], o[dt][qg][1] * inv[qg]);
            ((h16x2*)&v4)[1] = __builtin_amdgcn_cvt_pkrtz(
                o[dt][qg][2] * inv[qg], o[dt][qg][3] * inv[qg]);
            *(f16x4*)(ctx + (size_t)(qbase + qg * 16 + l15) * (NH * HD)
                          + h * HD + dt * 16 + quad * 4) = v4;
        }
}

// ---------------- launch ----------------
extern "C" void kernel_launch(void* const* d_in, const int* in_sizes, int n_in,
                              void* d_out, int out_size, void* d_ws, size_t ws_size,
                              hipStream_t stream) {
    const float* x    = (const float*)d_in[0];
    const float* mask = (const float*)d_in[1];
    const int*   pos  = (const int*)  d_in[2];
    const float* wq   = (const float*)d_in[3];
    const float* wk   = (const float*)d_in[4];
    const float* wv   = (const float*)d_in[5];
    const float* wo   = (const float*)d_in[6];
    float* out = (float*)d_out;

    char* ws = (char*)d_ws;
    // phase 1-2: xb [0,8M), Wcat [8,20M), woT [20,28M), Qb [28,36M),
    //            Kb [36,38M), VTb [38,40M)
    // phase 3:   ctx [0,8M) (xb dead after gemm0)
    // phase 4:   gemm1 reads ctx + woT
    f16*   xb    = (f16*)(ws);
    f16*   Wcat  = (f16*)(ws + ((size_t)8  << 20));
    f16*   woT   = (f16*)(ws + ((size_t)20 << 20));
    f16*   Qb    = (f16*)(ws + ((size_t)28 << 20));
    f16*   Kb    = (f16*)(ws + ((size_t)36 << 20));
    f16*   VTb   = (f16*)(ws + ((size_t)38 << 20));
    f16*   ctx   = (f16*)(ws);

    prep_all<<<dim3(64, 64, 5), dim3(32, 8), 0, stream>>>(
        x, wq, wk, wv, wo, xb, Wcat, woT);

    // fused Q/K/V projection + RoPE + mask-folded V: C[2048,3072] = xb @ Wcat^T
    gemm_bt<0><<<dim3(3072 / 128, 2048 / 64), 256, 0, stream>>>(
        xb, Wcat, nullptr, Qb, Kb, VTb, pos, mask, 3072, 2048);

    attn_fused<<<dim3(SEQ / 256, NH), 512, 0, stream>>>(
        Qb, Kb, VTb, mask, ctx);

    // out = ctx @ wo (fp32 direct)
    gemm_bt<1><<<dim3(2048 / 128, 2048 / 64), 256, 0, stream>>>(
        ctx, woT, out, nullptr, nullptr, nullptr, nullptr, nullptr, 2048, 2048);
}